// Round 9
// baseline (536.818 us; speedup 1.0000x reference)
//
#include <hip/hip_runtime.h>
#include <math.h>

// ---------------- problem constants ----------------
#define NB 16
#define TT 12
#define H1B (47 * 46 * 32)          // 69184 per batch (layer1 plane)
#define H2B (46 * 44 * 32)          // 64768 per batch (layer2 plane)
#define H1SLOT (NB * H1B)           // 1106944
#define H2SLOT (NB * H2B)           // 1036288
#define XBSTRIDE (TT * 48 * 48 * 3) // 82944 per batch in x

typedef short short8v __attribute__((ext_vector_type(8)));
typedef float floatx4 __attribute__((ext_vector_type(4)));

__device__ __forceinline__ short f2bf(float x) {
    unsigned u = __float_as_uint(x);
    u = (u + 0x7FFFu + ((u >> 16) & 1u)) >> 16;   // RNE
    return (short)u;
}
__device__ __forceinline__ float bf2f(short s) {
    return __uint_as_float(((unsigned)(unsigned short)s) << 16);
}
__device__ __forceinline__ float hsig(float z) {
    return fminf(fmaxf(0.2f * z + 0.5f, 0.f), 1.f);
}

// ---------------------------------------------------------------------------
__global__ __launch_bounds__(256) void convert_x(const float* __restrict__ x,
                                                 short* __restrict__ xbf, int n) {
    int i = blockIdx.x * 256 + threadIdx.x;
    if (i < n) xbf[i] = f2bf(x[i]);
}

// Weights -> MFMA B-fragment layout, bf16 (same as R2..R7).
__global__ __launch_bounds__(256) void transform_w(
    const float* __restrict__ W1s, const float* __restrict__ U1s,
    const float* __restrict__ W2s, const float* __restrict__ U2s,
    short* __restrict__ Bt1, short* __restrict__ Bt2)
{
    int idx = blockIdx.x * 256 + threadIdx.x;       // 0..77823
    int layer2 = idx >= 28672;
    int i = layer2 ? idx - 28672 : idx;
    int ci = i & 31, j = (i >> 5) & 15, g = (i >> 9) & 3, fh = (i >> 11) & 1, c = i >> 12;
    int col = g * 32 + fh * 16 + j;
    float v = 0.f;
    if (!layer2) {
        if (c == 0) {
            if (ci < 18) { int kk = ci / 3, cc = ci - kk * 3; v = W1s[(kk * 3 + cc) * 128 + col]; }
        } else {
            v = U1s[((c - 1) * 32 + ci) * 128 + col];
        }
    } else {
        if (c < 6) v = W2s[(c * 32 + ci) * 128 + col];
        else       v = U2s[((c - 6) * 32 + ci) * 128 + col];
    }
    (layer2 ? Bt2 : Bt1)[i] = f2bf(v);
}

// ---------------------------------------------------------------------------
// Two-timestep ConvLSTM block (layer 1).
// Step A (t=tA): ring 5x18 (M=96, 6 frags); step B (t=tA+1): core 4x16.
// Intermediate h-ring and c stay in LDS.
// ---------------------------------------------------------------------------
__device__ __forceinline__ void l1_block(
    const short* __restrict__ xbf,
    const short* __restrict__ h1rec,   // h1(tA-1), global
    short* __restrict__ h1wA,          // h1(tA) core out
    short* __restrict__ h1wB,          // h1(tA+1) core out
    const float* __restrict__ c1r, float* __restrict__ c1w,
    const short* __restrict__ Bt, const float* __restrict__ bias,
    int b, int y0, int x0, int tA, short* lds)
{
    short* REC = lds;                  // 120*40 = 4800 (h1(tA-1) 6x20, origin y0, x0-2)
    short* X1  = lds + 4800;           // 96*40  = 3840 (im2col x(tA), ring M=96)
    short* H   = lds + 4800;           // 90*40  = 3600 (h1(tA) ring) -- reuses X1
    short* X2  = lds;                  // 64*40  = 2560 (im2col x(tA+1)) -- reuses REC
    float* CL  = (float*)(lds + 8640); // 64*32  = 2048 floats (c(tA) core)

    const int tid = threadIdx.x;
    const int lane = tid & 63;
    const int fh = tid >> 6;
    const int tx = lane & 15, q = lane >> 4;
    const int f = fh * 16 + tx;
    const short8v z8 = (short8v)0;

    // ---- stage h1(tA-1): rows y0..y0+5, cols x0-2..x0+17, zero-pad ----
    {
        const short* hrb = h1rec + b * H1B;
        for (int i = tid; i < 480; i += 128) {
            int p = i >> 2, c4 = i & 3;
            int row = p / 20, col = p - row * 20;
            int y = y0 + row, x = x0 - 2 + col;
            short8v v = z8;
            if (y < 47 && (unsigned)x < 46u)
                v = *(const short8v*)(hrb + (y * 46 + x) * 32 + c4 * 8);
            *(short8v*)&REC[p * 40 + c4 * 8] = v;
        }
    }
    // ---- im2col x(tA) at ring positions p=0..89 (pad M to 96) ----
    {
        const short* xb = xbf + b * XBSTRIDE + tA * 6912;
        for (int i = tid; i < 3072; i += 128) {
            int m = i >> 5, k2 = i & 31;
            short v = 0;
            if (k2 < 18 && m < 90) {
                int kk = k2 / 3, cc = k2 - kk * 3;
                int ky = (kk >= 3) ? 1 : 0, kx = kk - ky * 3;
                int row = m / 18, col = m - row * 18;
                int ys = y0 + row + ky; if (ys > 47) ys = 47;
                int xs = x0 - 1 + col + kx; if (xs < 0) xs = 0; if (xs > 47) xs = 47;
                v = xb[(ys * 48 + xs) * 3 + cc];
            }
            X1[m * 40 + k2] = v;
        }
    }
    __syncthreads();

    int baseA[6];
#pragma unroll
    for (int a = 0; a < 6; ++a) {
        int p = a * 16 + tx;
        baseA[a] = ((p / 18) * 20 + (p % 18)) * 40 + q * 8;
    }
    const short* Btl = Bt + fh * 2048 + tx * 32 + q * 8;

    // ---- K-loop A: ring M=96, NCH=7 ----
    floatx4 acc[6][4] = {};
#pragma unroll
    for (int c = 0; c < 7; ++c) {
        short8v bf4[4], af[6];
#pragma unroll
        for (int g = 0; g < 4; ++g)
            bf4[g] = *(const short8v*)(Btl + c * 4096 + g * 512);
        if (c == 0) {
#pragma unroll
            for (int a = 0; a < 6; ++a)
                af[a] = *(const short8v*)&X1[(a * 16 + tx) * 40 + q * 8];
        } else {
            int kk = c - 1;
            int ky = (kk >= 3) ? 1 : 0, kx = kk - ky * 3;
            int off = (ky * 20 + kx) * 40;
#pragma unroll
            for (int a = 0; a < 6; ++a)
                af[a] = *(const short8v*)&REC[baseA[a] + off];
        }
#pragma unroll
        for (int a = 0; a < 6; ++a)
#pragma unroll
            for (int g = 0; g < 4; ++g)
                acc[a][g] = __builtin_amdgcn_mfma_f32_16x16x32_bf16(af[a], bf4[g], acc[a][g], 0, 0, 0);
    }
    __syncthreads();   // K-loop A LDS reads complete (X1, REC now dead)

    // ---- stage im2col x(tA+1) core (over REC) ----
    {
        const short* xb2 = xbf + b * XBSTRIDE + (tA + 1) * 6912;
        for (int i = tid; i < 2048; i += 128) {
            int m = i >> 5, k2 = i & 31;
            short v = 0;
            if (k2 < 18) {
                int kk = k2 / 3, cc = k2 - kk * 3;
                int ky = (kk >= 3) ? 1 : 0, kx = kk - ky * 3;
                int ys = y0 + (m >> 4) + ky; if (ys > 47) ys = 47;
                int xs = x0 + (m & 15) + kx; if (xs > 47) xs = 47;
                v = xb2[(ys * 48 + xs) * 3 + cc];
            }
            X2[m * 40 + k2] = v;
        }
    }

    // ---- epilogue A: gate math on ring, h->H(LDS)+core global, c->CL(LDS) ----
    {
        const float bi = bias[f], bf_ = bias[32 + f], bc_ = bias[64 + f], bo_ = bias[96 + f];
        const float* crb = c1r + b * H1B;
#pragma unroll
        for (int a = 0; a < 6; ++a) {
#pragma unroll
            for (int r = 0; r < 4; ++r) {
                int p = a * 16 + q * 4 + r;
                int row = p / 18, col = p - row * 18;
                int y = y0 + row, xe = x0 - 1 + col;
                bool inb = (p < 90) && (y < 47) && ((unsigned)xe < 46u);
                float cg = inb ? crb[(y * 46 + xe) * 32 + f] : 0.f;
                float ig = hsig(acc[a][0][r] + bi);
                float fg = hsig(acc[a][1][r] + bf_);
                float gg = fmaxf(acc[a][2][r] + bc_, 0.f);
                float og = hsig(acc[a][3][r] + bo_);
                float cn = fg * cg + ig * gg;
                short hb = inb ? f2bf(og * fmaxf(cn, 0.f)) : (short)0;
                if (p < 90) H[p * 40 + f] = hb;
                if (inb && row < 4 && col >= 1 && col <= 16) {
                    h1wA[b * H1B + (y * 46 + xe) * 32 + f] = hb;
                    CL[(row * 16 + (col - 1)) * 32 + f] = cn;
                }
            }
        }
    }
    __syncthreads();

    // ---- K-loop B: core M=64, NCH=7, A from LDS (X2 + H) ----
    floatx4 ac2[4][4] = {};
#pragma unroll
    for (int c = 0; c < 7; ++c) {
        short8v bf4[4], af[4];
#pragma unroll
        for (int g = 0; g < 4; ++g)
            bf4[g] = *(const short8v*)(Btl + c * 4096 + g * 512);
        if (c == 0) {
#pragma unroll
            for (int a = 0; a < 4; ++a)
                af[a] = *(const short8v*)&X2[(a * 16 + tx) * 40 + q * 8];
        } else {
            int kk = c - 1;
            int ky = (kk >= 3) ? 1 : 0, kx = kk - ky * 3;
#pragma unroll
            for (int a = 0; a < 4; ++a)
                af[a] = *(const short8v*)&H[((a + ky) * 18 + tx + kx) * 40 + q * 8];
        }
#pragma unroll
        for (int a = 0; a < 4; ++a)
#pragma unroll
            for (int g = 0; g < 4; ++g)
                ac2[a][g] = __builtin_amdgcn_mfma_f32_16x16x32_bf16(af[a], bf4[g], ac2[a][g], 0, 0, 0);
    }

    // ---- epilogue B: core, write h1(tA+1) + c1(tA+1) to global ----
    {
        const float bi = bias[f], bf_ = bias[32 + f], bc_ = bias[64 + f], bo_ = bias[96 + f];
#pragma unroll
        for (int a = 0; a < 4; ++a) {
            int y = y0 + a;
#pragma unroll
            for (int r = 0; r < 4; ++r) {
                int xe = x0 + q * 4 + r;
                if (y < 47 && xe < 46) {
                    float cg = CL[(a * 16 + q * 4 + r) * 32 + f];
                    float ig = hsig(ac2[a][0][r] + bi);
                    float fg = hsig(ac2[a][1][r] + bf_);
                    float gg = fmaxf(ac2[a][2][r] + bc_, 0.f);
                    float og = hsig(ac2[a][3][r] + bo_);
                    float cn = fg * cg + ig * gg;
                    int o = b * H1B + (y * 46 + xe) * 32 + f;
                    c1w[o] = cn;
                    h1wB[o] = f2bf(og * fmaxf(cn, 0.f));
                }
            }
        }
    }
}

// ---------------------------------------------------------------------------
// Two-timestep ConvLSTM block (layer 2) + MaxPool for both steps.
// ---------------------------------------------------------------------------
__device__ __forceinline__ void l2_block(
    const short* __restrict__ h1inA,   // h1(tA) global
    const short* __restrict__ h1inB,   // h1(tA+1) global
    const short* __restrict__ h2rec,   // h2(tA-1) global
    short* __restrict__ h2wB,          // h2(tA+1) core out
    const float* __restrict__ c2r, float* __restrict__ c2w,
    const short* __restrict__ Bt, const float* __restrict__ bias,
    short* __restrict__ pool,
    int b, int y0, int x0, int tA, short* lds)
{
    short* REC = lds;                  // 120*40 (h2(tA-1) 6x20, origin y0, x0-2)
    short* IN1 = lds + 4800;           // 120*40 (h1(tA) 6x20, origin y0, x0-1)
    short* H   = lds + 4800;           // 90*40 (h2(tA) ring) -- reuses IN1
    short* IN2 = lds;                  // 90*40 (h1(tA+1) 5x18, origin y0, x0) -- reuses REC
    float* CL  = (float*)(lds + 9600); // 2048 floats (c2(tA) core)

    const int tid = threadIdx.x;
    const int lane = tid & 63;
    const int fh = tid >> 6;
    const int tx = lane & 15, q = lane >> 4;
    const int f = fh * 16 + tx;
    const short8v z8 = (short8v)0;

    // ---- stage h2(tA-1): rows y0..y0+5, cols x0-2..x0+17, zero-pad ----
    {
        const short* hrb = h2rec + b * H2B;
        for (int i = tid; i < 480; i += 128) {
            int p = i >> 2, c4 = i & 3;
            int row = p / 20, col = p - row * 20;
            int y = y0 + row, x = x0 - 2 + col;
            short8v v = z8;
            if (y < 46 && (unsigned)x < 44u)
                v = *(const short8v*)(hrb + (y * 44 + x) * 32 + c4 * 8);
            *(short8v*)&REC[p * 40 + c4 * 8] = v;
        }
    }
    // ---- stage h1(tA): rows y0..y0+5 (clamp), cols x0-1..x0+18 (clamp) ----
    {
        const short* ib = h1inA + b * H1B;
        for (int i = tid; i < 480; i += 128) {
            int p = i >> 2, c4 = i & 3;
            int row = p / 20, col = p - row * 20;
            int ys = y0 + row; if (ys > 46) ys = 46;
            int xs = x0 - 1 + col; if (xs < 0) xs = 0; if (xs > 45) xs = 45;
            *(short8v*)&IN1[p * 40 + c4 * 8] =
                *(const short8v*)(ib + (ys * 46 + xs) * 32 + c4 * 8);
        }
    }
    __syncthreads();

    int baseA[6];
#pragma unroll
    for (int a = 0; a < 6; ++a) {
        int p = a * 16 + tx;
        baseA[a] = ((p / 18) * 20 + (p % 18)) * 40 + q * 8;
    }
    const short* Btl = Bt + fh * 2048 + tx * 32 + q * 8;

    // ---- K-loop A: ring M=96, NCH=12 (6 input + 6 recur) ----
    floatx4 acc[6][4] = {};
#pragma unroll
    for (int c = 0; c < 12; ++c) {
        short8v bf4[4], af[6];
#pragma unroll
        for (int g = 0; g < 4; ++g)
            bf4[g] = *(const short8v*)(Btl + c * 4096 + g * 512);
        int kk = (c < 6) ? c : (c - 6);
        int ky = (kk >= 3) ? 1 : 0, kx = kk - ky * 3;
        int off = (ky * 20 + kx) * 40;
        const short* src = (c < 6) ? IN1 : REC;
#pragma unroll
        for (int a = 0; a < 6; ++a)
            af[a] = *(const short8v*)&src[baseA[a] + off];
#pragma unroll
        for (int a = 0; a < 6; ++a)
#pragma unroll
            for (int g = 0; g < 4; ++g)
                acc[a][g] = __builtin_amdgcn_mfma_f32_16x16x32_bf16(af[a], bf4[g], acc[a][g], 0, 0, 0);
    }
    __syncthreads();   // K-loop A LDS reads complete

    // ---- stage h1(tA+1) core region (over REC): rows y0..y0+4, cols x0..x0+17 ----
    {
        const short* ib = h1inB + b * H1B;
        for (int i = tid; i < 360; i += 128) {
            int p = i >> 2, c4 = i & 3;
            int row = p / 18, col = p - row * 18;
            int ys = y0 + row; if (ys > 46) ys = 46;
            int xs = x0 + col; if (xs > 45) xs = 45;
            *(short8v*)&IN2[p * 40 + c4 * 8] =
                *(const short8v*)(ib + (ys * 46 + xs) * 32 + c4 * 8);
        }
    }

    // ---- epilogue A: ring gates, h->H(LDS only), c->CL(core) ----
    {
        const float bi = bias[f], bf_ = bias[32 + f], bc_ = bias[64 + f], bo_ = bias[96 + f];
        const float* crb = c2r + b * H2B;
#pragma unroll
        for (int a = 0; a < 6; ++a) {
#pragma unroll
            for (int r = 0; r < 4; ++r) {
                int p = a * 16 + q * 4 + r;
                int row = p / 18, col = p - row * 18;
                int y = y0 + row, xe = x0 - 1 + col;
                bool inb = (p < 90) && (y < 46) && ((unsigned)xe < 44u);
                float cg = inb ? crb[(y * 44 + xe) * 32 + f] : 0.f;
                float ig = hsig(acc[a][0][r] + bi);
                float fg = hsig(acc[a][1][r] + bf_);
                float gg = fmaxf(acc[a][2][r] + bc_, 0.f);
                float og = hsig(acc[a][3][r] + bo_);
                float cn = fg * cg + ig * gg;
                short hb = inb ? f2bf(og * fmaxf(cn, 0.f)) : (short)0;
                if (p < 90) H[p * 40 + f] = hb;
                if (inb && row < 4 && col >= 1 && col <= 16)
                    CL[(row * 16 + (col - 1)) * 32 + f] = cn;
            }
        }
    }
    __syncthreads();

    // ---- pool(tA) from H ring (core rows 0..3, cols 1..16) ----
    for (int i = tid; i < 512; i += 128) {
        int f2 = i & 31, cell = i >> 5;
        int ap = cell >> 3, j = cell & 7;
        int py = y0 / 2 + ap, px = x0 / 2 + j;
        if (py < 23 && px < 22) {
            int p00 = (2 * ap) * 18 + (1 + 2 * j);
            float m0 = bf2f(H[p00 * 40 + f2]),        m1 = bf2f(H[(p00 + 1) * 40 + f2]);
            float m2 = bf2f(H[(p00 + 18) * 40 + f2]), m3 = bf2f(H[(p00 + 19) * 40 + f2]);
            pool[(size_t)b * 194304 + ((tA * 23 + py) * 22 + px) * 32 + f2] =
                f2bf(fmaxf(fmaxf(m0, m1), fmaxf(m2, m3)));
        }
    }

    // ---- K-loop B: core M=64, NCH=12, A from LDS (IN2 + H) ----
    floatx4 ac2[4][4] = {};
#pragma unroll
    for (int c = 0; c < 12; ++c) {
        short8v bf4[4], af[4];
#pragma unroll
        for (int g = 0; g < 4; ++g)
            bf4[g] = *(const short8v*)(Btl + c * 4096 + g * 512);
        int kk = (c < 6) ? c : (c - 6);
        int ky = (kk >= 3) ? 1 : 0, kx = kk - ky * 3;
        const short* src = (c < 6) ? IN2 : H;
#pragma unroll
        for (int a = 0; a < 4; ++a)
            af[a] = *(const short8v*)&src[((a + ky) * 18 + tx + kx) * 40 + q * 8];
#pragma unroll
        for (int a = 0; a < 4; ++a)
#pragma unroll
            for (int g = 0; g < 4; ++g)
                ac2[a][g] = __builtin_amdgcn_mfma_f32_16x16x32_bf16(af[a], bf4[g], ac2[a][g], 0, 0, 0);
    }

    // ---- epilogue B: core h2(tA+1)/c2(tA+1) to global + pool(tA+1) ----
    {
        const float bi = bias[f], bf_ = bias[32 + f], bc_ = bias[64 + f], bo_ = bias[96 + f];
        float hv[4][4];
#pragma unroll
        for (int a = 0; a < 4; ++a) {
            int y = y0 + a;
#pragma unroll
            for (int r = 0; r < 4; ++r) {
                int xe = x0 + q * 4 + r;
                float hn = 0.f;
                if (y < 46 && xe < 44) {
                    float cg = CL[(a * 16 + q * 4 + r) * 32 + f];
                    float ig = hsig(ac2[a][0][r] + bi);
                    float fg = hsig(ac2[a][1][r] + bf_);
                    float gg = fmaxf(ac2[a][2][r] + bc_, 0.f);
                    float og = hsig(ac2[a][3][r] + bo_);
                    float cn = fg * cg + ig * gg;
                    int o = b * H2B + (y * 44 + xe) * 32 + f;
                    c2w[o] = cn;
                    short hb = f2bf(og * fmaxf(cn, 0.f));
                    h2wB[o] = hb;
                    hn = bf2f(hb);
                }
                hv[a][r] = hn;
            }
        }
#pragma unroll
        for (int ap = 0; ap < 2; ++ap) {
            int py = y0 / 2 + ap;
#pragma unroll
            for (int rp = 0; rp < 2; ++rp) {
                int px = x0 / 2 + q * 2 + rp;
                if (py < 23 && px < 22) {
                    float m = fmaxf(fmaxf(hv[2 * ap][2 * rp],     hv[2 * ap][2 * rp + 1]),
                                    fmaxf(hv[2 * ap + 1][2 * rp], hv[2 * ap + 1][2 * rp + 1]));
                    pool[(size_t)b * 194304 + (((tA + 1) * 23 + py) * 22 + px) * 32 + f] = f2bf(m);
                }
            }
        }
    }
}

// ---------------------------------------------------------------------------
// Fused 2-step pipeline kernel. 1152 blocks x 128 thr.
// gid: layer=gid&1, b=(gid>>1)&15, tile=gid>>5 (0..35): y0=(tile/3)*4, x0=(tile%3)*16
// ---------------------------------------------------------------------------
__global__ __launch_bounds__(128) void fused2(
    const short* __restrict__ xbf,
    const short* __restrict__ h1rec, short* __restrict__ h1wA, short* __restrict__ h1wB,
    const short* __restrict__ h1inA, const short* __restrict__ h1inB,
    const short* __restrict__ h2rec, short* __restrict__ h2wB,
    const short* __restrict__ Bt1, const short* __restrict__ Bt2,
    const float* __restrict__ b1, const float* __restrict__ b2,
    const float* __restrict__ c1r, float* __restrict__ c1w,
    const float* __restrict__ c2r, float* __restrict__ c2w,
    short* __restrict__ pool, int tA1, int tA2)
{
    __shared__ short lds[13696];      // 27.4 KB
    int gid = blockIdx.x;
    int layer = gid & 1;
    int b = (gid >> 1) & 15;
    int tile = gid >> 5;
    int y0 = (tile / 3) * 4;
    int x0 = (tile % 3) * 16;

    if (layer == 0) {
        if (tA1 >= TT) return;
        l1_block(xbf, h1rec, h1wA, h1wB, c1r, c1w, Bt1, b1, b, y0, x0, tA1, lds);
    } else {
        if (tA2 < 0) return;
        l2_block(h1inA, h1inB, h2rec, h2wB, c2r, c2w, Bt2, b2, pool, b, y0, x0, tA2, lds);
    }
}

// ---------------------------------------------------------------------------
__global__ __launch_bounds__(256) void gemv_kernel(
    const short* __restrict__ p, const float* __restrict__ Wd1, float* __restrict__ d1)
{
    int by = blockIdx.y;
    int k0 = blockIdx.x * 3036;
    float part[4][10];
#pragma unroll
    for (int bb = 0; bb < 4; bb++)
#pragma unroll
        for (int j = 0; j < 10; j++) part[bb][j] = 0.f;

    for (int k = k0 + threadIdx.x; k < k0 + 3036; k += 256) {
        const float* wr = Wd1 + (size_t)k * 10;
        float wv[10];
#pragma unroll
        for (int j = 0; j < 10; j++) wv[j] = wr[j];
#pragma unroll
        for (int bb = 0; bb < 4; bb++) {
            float m = bf2f(p[(size_t)(by * 4 + bb) * 194304 + k]);
#pragma unroll
            for (int j = 0; j < 10; j++) part[bb][j] = fmaf(m, wv[j], part[bb][j]);
        }
    }
    __shared__ float red[4][10][4];
    int lane = threadIdx.x & 63, wv2 = threadIdx.x >> 6;
#pragma unroll
    for (int bb = 0; bb < 4; bb++)
#pragma unroll
        for (int j = 0; j < 10; j++) {
            float v = part[bb][j];
            for (int off = 32; off > 0; off >>= 1) v += __shfl_down(v, off);
            if (lane == 0) red[bb][j][wv2] = v;
        }
    __syncthreads();
    if (threadIdx.x < 40) {
        int bb = threadIdx.x / 10, j = threadIdx.x % 10;
        float s = red[bb][j][0] + red[bb][j][1] + red[bb][j][2] + red[bb][j][3];
        atomicAdd(&d1[(bb + 4 * 0 + by * 4) * 10 + j], s);
    }
}

__global__ void final_dense(const float* __restrict__ d1, const float* __restrict__ bd1,
                            const float* __restrict__ Wd2, const float* __restrict__ bd2,
                            float* __restrict__ out)
{
    int b = threadIdx.x;
    if (b < NB) {
        float s = bd2[0];
#pragma unroll
        for (int j = 0; j < 10; j++) s += (d1[b * 10 + j] + bd1[j]) * Wd2[j];
        out[b] = s;
    }
}

// ---------------------------------------------------------------------------
extern "C" void kernel_launch(void* const* d_in, const int* in_sizes, int n_in,
                              void* d_out, int out_size, void* d_ws, size_t ws_size,
                              hipStream_t stream)
{
    const float* x   = (const float*)d_in[0];
    const float* W1s = (const float*)d_in[1];
    const float* U1s = (const float*)d_in[2];
    const float* b1  = (const float*)d_in[3];
    const float* W2s = (const float*)d_in[4];
    const float* U2s = (const float*)d_in[5];
    const float* b2  = (const float*)d_in[6];
    const float* Wd1 = (const float*)d_in[7];
    const float* bd1 = (const float*)d_in[8];
    const float* Wd2 = (const float*)d_in[9];
    const float* bd2 = (const float*)d_in[10];
    float* out = (float*)d_out;

    short* Bt1 = (short*)d_ws;            // 28672
    short* Bt2 = Bt1 + 28672;             // 49152
    short* xbf = Bt2 + 49152;             // 1327104
    short* p   = xbf + 1327104;           // 3108864
    short* zr  = p + 3108864;             // ---- zero region ----
    short* h1s[4]; for (int i = 0; i < 4; i++) h1s[i] = zr + (size_t)i * H1SLOT;
    short* h2base = zr + 4 * (size_t)H1SLOT;
    short* h2s[3]; for (int i = 0; i < 3; i++) h2s[i] = h2base + (size_t)i * H2SLOT;
    float* c1s[2]; c1s[0] = (float*)(h2base + 3 * (size_t)H2SLOT);
    c1s[1] = c1s[0] + H1SLOT;
    float* c2s[2]; c2s[0] = c1s[1] + H1SLOT;
    c2s[1] = c2s[0] + H2SLOT;
    float* d1 = c2s[1] + H2SLOT;          // 160 floats
    size_t zero_bytes = (size_t)(4 * H1SLOT + 3 * H2SLOT) * 2
                      + (size_t)(2 * H1SLOT + 2 * H2SLOT + 160) * 4;

    hipMemsetAsync(zr, 0, zero_bytes, stream);
    convert_x<<<(1327104 + 255) / 256, 256, 0, stream>>>(x, xbf, 1327104);
    transform_w<<<304, 256, 0, stream>>>(W1s, U1s, W2s, U2s, Bt1, Bt2);

    // 7 kernels: kernel k runs L1 t=2k,2k+1 and L2 t=2k-2,2k-1
    for (int k = 0; k < 7; ++k) {
        int tA1 = 2 * k, tA2 = 2 * k - 2;
        auto s3 = [](int t) { return ((t % 3) + 3) % 3; };
        const short* h1rec = h1s[(2 * k - 1) & 3];
        short* h1wA = h1s[(2 * k) & 3];
        short* h1wB = h1s[(2 * k + 1) & 3];
        const short* h1inA = h1s[(2 * k - 2) & 3];
        const short* h1inB = h1s[(2 * k - 1) & 3];
        const short* h2rec = h2s[s3(2 * k - 3)];
        short* h2wB = h2s[s3(2 * k - 1)];
        const float* c1r = c1s[(k + 1) & 1];
        float* c1w = c1s[k & 1];
        const float* c2r = c2s[(k + 1) & 1];
        float* c2w = c2s[k & 1];
        fused2<<<dim3(1152), 128, 0, stream>>>(
            xbf, h1rec, h1wA, h1wB, h1inA, h1inB, h2rec, h2wB,
            Bt1, Bt2, b1, b2, c1r, c1w, c2r, c2w, p, tA1, tA2);
    }

    gemv_kernel<<<dim3(64, 4), 256, 0, stream>>>(p, Wd1, d1);
    final_dense<<<1, 64, 0, stream>>>(d1, bd1, Wd2, bd2, out);
}

// Round 10
// 311.886 us; speedup vs baseline: 1.7212x; 1.7212x over previous
//
#include <hip/hip_runtime.h>
#include <math.h>

// ---------------- problem constants ----------------
#define NB 16
#define TT 12
#define H1 47
#define W1D 46
#define H2 46
#define W2D 44

typedef short short8v __attribute__((ext_vector_type(8)));
typedef float floatx4 __attribute__((ext_vector_type(4)));

__device__ __forceinline__ short f2bf(float x) {
    unsigned u = __float_as_uint(x);
    u = (u + 0x7FFFu + ((u >> 16) & 1u)) >> 16;   // RNE
    return (short)u;
}
__device__ __forceinline__ float bf2f(short s) {
    return __uint_as_float(((unsigned)(unsigned short)s) << 16);
}
__device__ __forceinline__ float hsig(float z) {
    return fminf(fmaxf(0.2f * z + 0.5f, 0.f), 1.f);
}

// ---------------------------------------------------------------------------
__global__ __launch_bounds__(256) void convert_x(const float* __restrict__ x,
                                                 short* __restrict__ xbf, int n) {
    int i = blockIdx.x * 256 + threadIdx.x;
    if (i < n) xbf[i] = f2bf(x[i]);
}

// Weights -> MFMA B-fragment layout, bf16 (same as R2..R7).
// flat idx = ((c*2+fh)*4+g)*512 + j*32 + ci ; column = g*32+fh*16+j, k = ci
__global__ __launch_bounds__(256) void transform_w(
    const float* __restrict__ W1s, const float* __restrict__ U1s,
    const float* __restrict__ W2s, const float* __restrict__ U2s,
    short* __restrict__ Bt1, short* __restrict__ Bt2)
{
    int idx = blockIdx.x * 256 + threadIdx.x;       // 0..77823
    int layer2 = idx >= 28672;
    int i = layer2 ? idx - 28672 : idx;
    int ci = i & 31, j = (i >> 5) & 15, g = (i >> 9) & 3, fh = (i >> 11) & 1, c = i >> 12;
    int col = g * 32 + fh * 16 + j;
    float v = 0.f;
    if (!layer2) {
        if (c == 0) {
            if (ci < 18) { int kk = ci / 3, cc = ci - kk * 3; v = W1s[(kk * 3 + cc) * 128 + col]; }
        } else {
            v = U1s[((c - 1) * 32 + ci) * 128 + col];
        }
    } else {
        if (c < 6) v = W2s[(c * 32 + ci) * 128 + col];
        else       v = U2s[((c - 6) * 32 + ci) * 128 + col];
    }
    (layer2 ? Bt2 : Bt1)[i] = f2bf(v);
}

// ---------------------------------------------------------------------------
// One ConvLSTM timestep body (identical math to R7, which passed at 301us).
// Block = 128 thr = 2 waves (fh halves). Tile 4 rows x 16 cols.
// A-operands staged in LDS (zeros baked in); K-loop VMEM = B-frags only.
// cst packed per-thread. `first`: recurrent h = 0 and cell = 0 (cold start,
// bit-identical to reading a zeroed buffer).
// ---------------------------------------------------------------------------
template<int LAYER>
__device__ __forceinline__ void step_body(
    const short* __restrict__ xin,     // L1: xbf ; L2: h1 current (bf16)
    const short* __restrict__ hprev,   // recurrent h (bf16)
    const short* __restrict__ Bt,
    const float* __restrict__ bias,
    float* __restrict__ cstp,          // packed: + tid*16 + a*4 + r
    short* __restrict__ hnext,
    short* __restrict__ pool, int t2, int t1, int first,
    int b, int y0, int x0, short* ldsrec, short* ldsaux)
{
    constexpr int Ho   = (LAYER == 1) ? H1 : H2;
    constexpr int Wo   = (LAYER == 1) ? W1D : W2D;
    constexpr int NCH  = (LAYER == 1) ? 7 : 12;
    constexpr int REC0 = (LAYER == 1) ? 1 : 6;
    constexpr int IBS  = (LAYER == 1) ? (TT * 48 * 48 * 3) : (H1 * W1D * 32);
    constexpr int HBS  = Ho * Wo * 32;

    const int tid = threadIdx.x;
    const int lane = tid & 63;
    const int fh = tid >> 6;
    const int tx = lane & 15, q = lane >> 4;
    const short8v z8 = (short8v)0;

    // ---- stage recurrent tile: rows y0..y0+4, cols x0-1..x0+16, SAME-pad zeros ----
    {
        const short* hb0 = hprev + b * HBS;
        for (int i = tid; i < 360; i += 128) {        // 90 pos x 4 chunks(16B)
            int p = i >> 2, c4 = i & 3;
            int row = p / 18, col = p - row * 18;
            int y = y0 + row, x = x0 + col - 1;
            short8v v = z8;
            if (!first && y < Ho && (unsigned)x < (unsigned)Wo)
                v = *(const short8v*)(hb0 + (y * Wo + x) * 32 + c4 * 8);
            *(short8v*)&ldsrec[p * 40 + c4 * 8] = v;
        }
    }

    if (LAYER == 1) {
        // padded im2col of x: m=0..63 (4x16 tile), k=kk*3+cc (18 -> pad 32)
        const short* xb0 = xin + b * IBS + t1 * 6912;
        for (int i = tid; i < 64 * 32; i += 128) {
            int m = i >> 5, k = i & 31;
            short v = 0;
            if (k < 18) {
                int kk = k / 3, cc = k - kk * 3;
                int ky = (kk >= 3) ? 1 : 0, kx = kk - ky * 3;
                int ys = y0 + (m >> 4) + ky; if (ys > 47) ys = 47;
                int xs = x0 + (m & 15) + kx; if (xs > 47) xs = 47;
                v = xb0[(ys * 48 + xs) * 3 + cc];
            }
            ldsaux[m * 40 + k] = v;
        }
    } else {
        // stage input-conv source tile: rows y0..y0+4 (clamped), cols x0..x0+17
        // (OOB cols land in slack; garbage feeds only masked outputs)
        const short* ib0 = xin + b * IBS;
        for (int i = tid; i < 360; i += 128) {
            int p = i >> 2, c4 = i & 3;
            int row = p / 18, col = p - row * 18;
            int ys = y0 + row; if (ys > H1 - 1) ys = H1 - 1;
            int xs = x0 + col;
            short8v v = *(const short8v*)(ib0 + (ys * W1D + xs) * 32 + c4 * 8);
            *(short8v*)&ldsaux[p * 40 + c4 * 8] = v;
        }
    }
    __syncthreads();

    const short* Btl = Bt + fh * 2048 + tx * 32 + q * 8;
    floatx4 acc[4][4] = {};   // [a(row)][gate]

#pragma unroll
    for (int c = 0; c < NCH; ++c) {
        short8v bf4[4], af[4];
#pragma unroll
        for (int g = 0; g < 4; ++g)
            bf4[g] = *(const short8v*)(Btl + c * 4096 + g * 512);

        if (LAYER == 1 && c == 0) {
#pragma unroll
            for (int a = 0; a < 4; ++a)
                af[a] = *(const short8v*)&ldsaux[(a * 16 + tx) * 40 + q * 8];
        } else if (LAYER == 2 && c < REC0) {
            int ky = (c >= 3) ? 1 : 0, kx = c - ky * 3;
#pragma unroll
            for (int a = 0; a < 4; ++a)
                af[a] = *(const short8v*)&ldsaux[(((a + ky) * 18 + tx + kx)) * 40 + q * 8];
        } else {
            int kk = c - REC0;
            int ky = (kk >= 3) ? 1 : 0, kx = kk - ky * 3;
#pragma unroll
            for (int a = 0; a < 4; ++a)
                af[a] = *(const short8v*)&ldsrec[(((a + ky) * 18 + tx + kx)) * 40 + q * 8];
        }
#pragma unroll
        for (int a = 0; a < 4; ++a)
#pragma unroll
            for (int g = 0; g < 4; ++g)
                acc[a][g] = __builtin_amdgcn_mfma_f32_16x16x32_bf16(af[a], bf4[g], acc[a][g], 0, 0, 0);
    }

    // ---- fused LSTM epilogue (C layout: M=q*4+r -> x, N=tx(+fh*16) -> f) ----
    const int f = fh * 16 + tx;
    const float bi = bias[f], bfv = bias[32 + f], bcv = bias[64 + f], bov = bias[96 + f];
    float* cme = cstp + tid * 16;
    float hv[4][4];
#pragma unroll
    for (int a = 0; a < 4; ++a) {
        int y = y0 + a;
        bool yok = y < Ho;
        floatx4 cold;
        if (first) { cold[0] = cold[1] = cold[2] = cold[3] = 0.f; }
        else         cold = *(floatx4*)(cme + a * 4);
        floatx4 cnew;
#pragma unroll
        for (int r = 0; r < 4; ++r) {
            int xe = x0 + q * 4 + r;
            float ig = hsig(acc[a][0][r] + bi);
            float fg = hsig(acc[a][1][r] + bfv);
            float gg = fmaxf(acc[a][2][r] + bcv, 0.f);
            float og = hsig(acc[a][3][r] + bov);
            float cn = fg * cold[r] + ig * gg;
            cnew[r] = cn;
            float hn = 0.f;
            if (yok && xe < Wo) {
                short hb = f2bf(og * fmaxf(cn, 0.f));
                hnext[b * HBS + (y * Wo + xe) * 32 + f] = hb;
                hn = bf2f(hb);
            }
            hv[a][r] = hn;
        }
        *(floatx4*)(cme + a * 4) = cnew;
    }

    if (LAYER == 2) {
        // MaxPool(2,2): row pairs (0,1),(2,3); col pairs within r
#pragma unroll
        for (int ap = 0; ap < 2; ++ap) {
            int py = y0 / 2 + ap;
#pragma unroll
            for (int rp = 0; rp < 2; ++rp) {
                int px = x0 / 2 + q * 2 + rp;
                if (py < 23 && px < 22) {
                    float m = fmaxf(fmaxf(hv[2 * ap][2 * rp],     hv[2 * ap][2 * rp + 1]),
                                    fmaxf(hv[2 * ap + 1][2 * rp], hv[2 * ap + 1][2 * rp + 1]));
                    pool[(size_t)b * 194304 + ((t2 * 23 + py) * 22 + px) * 32 + f] = f2bf(m);
                }
            }
        }
    }
}

// ---------------------------------------------------------------------------
// Fused pipeline step. grid = 1152 x 128 thr.
// gid: layer = gid&1 ; b = (gid>>1)&15 ; tile = gid>>5 (0..35)
// __launch_bounds__(128,3): VGPR<=170 -> >=6 blocks/CU -> all 1152 co-resident.
// ---------------------------------------------------------------------------
__global__ __launch_bounds__(128, 3) void fused_step(
    const short* __restrict__ xbf,
    const short* __restrict__ h1r, short* __restrict__ h1w,
    const short* __restrict__ h2r, short* __restrict__ h2w,
    const short* __restrict__ Bt1, const short* __restrict__ Bt2,
    const float* __restrict__ b1, const float* __restrict__ b2,
    float* __restrict__ c1, float* __restrict__ c2,
    short* __restrict__ pool, int t2, int t1,
    int do1, int do2, int first1, int first2)
{
    __shared__ short lds[7200];           // rec [3600] + aux [3600]
    int gid  = blockIdx.x;
    int layer = gid & 1;
    int b     = (gid >> 1) & 15;
    int t36   = gid >> 5;
    int y0 = (t36 / 3) * 4;
    int x0 = (t36 % 3) * 16;

    if (layer == 0) {
        if (!do1) return;
        float* cstp = c1 + (size_t)(b * 36 + t36) * 2048;
        step_body<1>(xbf, h1r, Bt1, b1, cstp, h1w, nullptr, 0, t1, first1,
                     b, y0, x0, lds, lds + 3600);
    } else {
        if (!do2) return;
        float* cstp = c2 + (size_t)(b * 36 + t36) * 2048;
        step_body<2>(h1r, h2r, Bt2, b2, cstp, h2w, pool, t2, 0, first2,
                     b, y0, x0, lds, lds + 3600);
    }
}

// ---------------------------------------------------------------------------
// gemv: one Wd1 sweep per batch-octet (x2 total). Non-atomic partials:
// d1p[(kc*2+grp)*80 + bb*10 + j], all slots written (no init needed).
// ---------------------------------------------------------------------------
__global__ __launch_bounds__(256) void gemv_kernel(
    const short* __restrict__ p, const float* __restrict__ Wd1, float* __restrict__ d1p)
{
    int grp = blockIdx.y;                // batches grp*8 .. grp*8+7
    int kc = blockIdx.x;                 // 0..63
    int k0 = kc * 3036;                  // 194304 / 64
    float part[8][10];
#pragma unroll
    for (int bb = 0; bb < 8; bb++)
#pragma unroll
        for (int j = 0; j < 10; j++) part[bb][j] = 0.f;

    for (int k = k0 + threadIdx.x; k < k0 + 3036; k += 256) {
        const float* wr = Wd1 + (size_t)k * 10;
        float wv[10];
#pragma unroll
        for (int j = 0; j < 10; j++) wv[j] = wr[j];
#pragma unroll
        for (int bb = 0; bb < 8; bb++) {
            float m = bf2f(p[(size_t)(grp * 8 + bb) * 194304 + k]);
#pragma unroll
            for (int j = 0; j < 10; j++) part[bb][j] = fmaf(m, wv[j], part[bb][j]);
        }
    }
    __shared__ float red[8][10][4];
    int lane = threadIdx.x & 63, wv2 = threadIdx.x >> 6;
#pragma unroll
    for (int bb = 0; bb < 8; bb++)
#pragma unroll
        for (int j = 0; j < 10; j++) {
            float v = part[bb][j];
            for (int off = 32; off > 0; off >>= 1) v += __shfl_down(v, off);
            if (lane == 0) red[bb][j][wv2] = v;
        }
    __syncthreads();
    if (threadIdx.x < 80) {
        int bb = threadIdx.x / 10, j = threadIdx.x % 10;
        d1p[(kc * 2 + grp) * 80 + bb * 10 + j] =
            red[bb][j][0] + red[bb][j][1] + red[bb][j][2] + red[bb][j][3];
    }
}

__global__ void final_dense(const float* __restrict__ d1p, const float* __restrict__ bd1,
                            const float* __restrict__ Wd2, const float* __restrict__ bd2,
                            float* __restrict__ out)
{
    __shared__ float dj[16][10];
    int tid = threadIdx.x;
    if (tid < 160) {
        int b = tid / 10, j = tid % 10, grp = b >> 3, bb = b & 7;
        float s = 0.f;
        for (int kc = 0; kc < 64; kc++)
            s += d1p[(kc * 2 + grp) * 80 + bb * 10 + j];
        dj[b][j] = s + bd1[j];
    }
    __syncthreads();
    if (tid < NB) {
        float s = bd2[0];
#pragma unroll
        for (int j = 0; j < 10; j++) s += dj[tid][j] * Wd2[j];
        out[tid] = s;
    }
}

// ---------------------------------------------------------------------------
extern "C" void kernel_launch(void* const* d_in, const int* in_sizes, int n_in,
                              void* d_out, int out_size, void* d_ws, size_t ws_size,
                              hipStream_t stream)
{
    const float* x   = (const float*)d_in[0];
    const float* W1s = (const float*)d_in[1];
    const float* U1s = (const float*)d_in[2];
    const float* b1  = (const float*)d_in[3];
    const float* W2s = (const float*)d_in[4];
    const float* U2s = (const float*)d_in[5];
    const float* b2  = (const float*)d_in[6];
    const float* Wd1 = (const float*)d_in[7];
    const float* bd1 = (const float*)d_in[8];
    const float* Wd2 = (const float*)d_in[9];
    const float* bd2 = (const float*)d_in[10];
    float* out = (float*)d_out;

    const int H1N = NB * H1 * W1D * 32;   // 1106944
    const int H2N = NB * H2 * W2D * 32;   // 1036288
    const int SLF = 32, SLB = 8192;
    const int SPAN1 = SLF + H1N + SLB;
    const int SPAN2 = SLF + H2N + SLB;
    const int CPL   = 16 * 36 * 2048;     // packed cst floats per layer

    short* Bt1 = (short*)d_ws;            // 28672
    short* Bt2 = Bt1 + 28672;             // 49152
    short* xbf = Bt2 + 49152;             // 1327104
    short* p   = xbf + 1327104;           // 3108864
    short* hr  = p + 3108864;
    short* h1a = hr + SLF;
    short* h1b = hr + SPAN1 + SLF;
    short* h2a = hr + 2 * SPAN1 + SLF;
    short* h2b = hr + 2 * SPAN1 + SPAN2 + SLF;
    float* c1  = (float*)(hr + 2 * SPAN1 + 2 * SPAN2);
    float* c2  = c1 + CPL;
    float* d1p = c2 + CPL;                // 10240 floats

    convert_x<<<(1327104 + 255) / 256, 256, 0, stream>>>(x, xbf, 1327104);
    transform_w<<<304, 256, 0, stream>>>(W1s, U1s, W2s, U2s, Bt1, Bt2);

    // software pipeline: kernel s runs L1(t=s) and L2(t=s-1)
    for (int s = 0; s <= TT; s++) {
        short*       h1w = (s & 1) ? h1b : h1a;
        const short* h1r = (s & 1) ? h1a : h1b;
        short*       h2w = (s & 1) ? h2a : h2b;
        const short* h2r = (s & 1) ? h2b : h2a;
        fused_step<<<dim3(1152), 128, 0, stream>>>(
            xbf, h1r, h1w, h2r, h2w, Bt1, Bt2, b1, b2, c1, c2,
            p, s - 1, (s < TT ? s : 0),
            (int)(s < TT), (int)(s >= 1), (int)(s == 0), (int)(s == 1));
    }

    gemv_kernel<<<dim3(64, 2), 256, 0, stream>>>(p, Wd1, d1p);
    final_dense<<<1, 192, 0, stream>>>(d1p, bd1, Wd2, bd2, out);
}